// Round 12
// baseline (272.544 us; speedup 1.0000x reference)
//
#include <hip/hip_runtime.h>
#include <hip/hip_bf16.h>
#include <cstdint>

typedef __bf16 bf16x8 __attribute__((ext_vector_type(8)));
typedef float  f32x4  __attribute__((ext_vector_type(4)));
typedef unsigned short u16x8 __attribute__((ext_vector_type(8)));

__device__ __forceinline__ unsigned short f2bf(float f) {
  __hip_bfloat16 h = __float2bfloat16(f);
  return __builtin_bit_cast(unsigned short, h);
}
__device__ __forceinline__ float bf2f(unsigned short u) {
  return __builtin_bit_cast(float, (unsigned)u << 16);
}

#define GL2LDS16(gp, lp)                                                      \
  __builtin_amdgcn_global_load_lds(                                           \
      (const __attribute__((address_space(1))) unsigned int*)(gp),            \
      (__attribute__((address_space(3))) unsigned int*)(lp), 16, 0, 0)

#define SBAR                                                                  \
  {                                                                           \
    __builtin_amdgcn_s_barrier();                                             \
    __builtin_amdgcn_sched_barrier(0);                                        \
  }
#define WAITV(n)                                                              \
  {                                                                           \
    asm volatile("s_waitcnt vmcnt(" #n ")" ::: "memory");                     \
    __builtin_amdgcn_sched_barrier(0);                                        \
  }
#define WAITL0                                                                \
  {                                                                           \
    asm volatile("s_waitcnt lgkmcnt(0)" ::: "memory");                        \
    __builtin_amdgcn_sched_barrier(0);                                        \
  }

// 256x256-tile GEMM, C[m][n] = sum_k A[m][k]*B[n][k] (B transposed layout).
// 16 waves (1024 threads), per-wave 64x64 (4Mx4N), BK=32, 3-slot LDS ring
// (3x32KB = 96KB), launch_bounds(1024,4) -> 64 VGPR (R9-measured; (1024,8)
// forced 32 VGPR and catastrophic spills, R10).
// K-loop = R9's verified single-barrier counted-vmcnt loop (best measured
// total, 245us). R12 change: LDS-STAGED COALESCED EPILOGUE. The old direct
// epilogue stored scattered 32B(bf16)/64B(f32) row-fragments -> measured
// WRITE_SIZE 1.76x logical (113MB vs 64MB) at a ~1.1TB/s cap on both
// ~100us dispatches. New epilogue: per 64-row chunk, waves scatter acc into
// an XOR-swizzled LDS chunk (phys = logical ^ ((row&7)<<5 bf16 / <<6 f32)),
// barrier, then 1024 threads drain full 512B/1KB row segments -> every HBM
// store is a whole aligned run in one row.
// Swizzle on staging: phys = l ^ (((l>>7)&3)<<4) on BOTH pre-swizzled
// global source and ds_read address (involution; measured 0 bank conflicts).
// Modes: 0 proj (col bias + elu+1, bf16)                      [Qp]
//        1 merged KV-proj (rows<1024: +bk, elu+1 -> KpT; else +bv -> VT)
//        3 split-K KVt partial (z=ks*4+b; K-window b*4096+ks*1024)
//        4 numerator (f32 out, /norm[row])
template <int MODE>
__global__ __launch_bounds__(1024, 4) void gemm256w(
    const unsigned short* __restrict__ A, long long lda, long long aOffZ,
    const unsigned short* __restrict__ B, long long ldb, long long bOffZ,
    void* __restrict__ C, long long ldc, long long cOffZ,
    const float* __restrict__ bias, const float* __restrict__ bias2,
    const float* __restrict__ norm, long long normOffZ, int K) {
  __shared__ __attribute__((aligned(16))) char lds[3 * 32768];
  const int t = threadIdx.x;
  const int wave = t >> 6, lane = t & 63;
  const int wm = wave >> 2, wn = wave & 3;  // 4M x 4N waves
  const int fr = lane & 15, fq = lane >> 4;

  // bijective XCD swizzle on flat xy block id (all grids here are %8==0)
  const int gx = gridDim.x, gy = gridDim.y;
  int flat = blockIdx.y * gx + blockIdx.x;
  const int total = gx * gy;
  if ((total & 7) == 0) flat = (flat & 7) * (total >> 3) + (flat >> 3);
  int bx, by;
  if (MODE == 1) {  // column-major decode: XCD owns few bx across all by
    bx = flat / gy;
    by = flat - bx * gy;
  } else {
    bx = flat % gx;
    by = flat / gx;
  }
  const int m0 = by * 256, n0 = bx * 256;

  const long long z = blockIdx.z;
  long long aBase, bBase;
  if (MODE == 3) {
    const long long koff = (z & 3) * 4096 + (z >> 2) * 1024;
    aBase = koff;
    bBase = koff;
  } else {
    aBase = z * aOffZ;
    bBase = z * bOffZ;
  }
  const unsigned short* Az = A + aBase;
  const unsigned short* Bz = B + bBase;

  // staging: thread t's 16B lands at linear sub-tile byte d = t*16 (16KB
  // sub-tile, 1024 threads); content there must be logical l = d^swz.
  const unsigned short* gA;
  const unsigned short* gB;
  {
    int d = t * 16;
    int l = d ^ (((d >> 7) & 3) << 4);
    int row = l >> 6, kel = (l & 63) >> 1;
    gA = Az + (long long)(m0 + row) * lda + kel;
    gB = Bz + (long long)(n0 + row) * ldb + kel;
  }

  // fragment read cores (swizzle folded; (row>>1)&3 == (fr>>1)&3)
  const int slotx = (fr >> 1) & 3;
  const int acore = wm * 4096 + fr * 64 + ((fq ^ slotx) << 4);
  const int bcore = 16384 + wn * 4096 + fr * 64 + ((fq ^ slotx) << 4);

  f32x4 acc[4][4];
#pragma unroll
  for (int i = 0; i < 4; ++i)
#pragma unroll
    for (int j = 0; j < 4; ++j) acc[i][j] = (f32x4){0.f, 0.f, 0.f, 0.f};

  const int NT = K >> 5;  // BK=32 K-tiles

  auto stage = [&](int tile) {
    char* sb = lds + (tile % 3) * 32768 + wave * 1024;
    const int k0 = tile << 5;
    GL2LDS16(gA + k0, sb);
    GL2LDS16(gB + k0, sb + 16384);
  };

  stage(0);
  stage(1);
  WAITV(2);  // tile 0's 2 loads landed (tile 1's may be outstanding)
  SBAR;

  bf16x8 av[4], bv[4];
  for (int tt = 0; tt < NT - 2; ++tt) {
    const char* sb = lds + (tt % 3) * 32768;
    stage(tt + 2);  // slot (tt+2)%3 == (tt-1)%3: retired+barriered in tt-1
#pragma unroll
    for (int i = 0; i < 4; ++i) {
      av[i] = *(const bf16x8*)(sb + acore + i * 1024);
      bv[i] = *(const bf16x8*)(sb + bcore + i * 1024);
    }
    WAITL0;  // own ds_reads retired (stage-safety requires this pre-barrier)
    __builtin_amdgcn_s_setprio(1);
#pragma unroll
    for (int mi = 0; mi < 4; ++mi)
#pragma unroll
      for (int ni = 0; ni < 4; ++ni)
        acc[mi][ni] = __builtin_amdgcn_mfma_f32_16x16x32_bf16(
            av[mi], bv[ni], acc[mi][ni], 0, 0, 0);
    __builtin_amdgcn_s_setprio(0);
    WAITV(2);  // retire tile tt+1's loads; barrier globalizes
    SBAR;
  }

  // tail tt = NT-2
  {
    const char* sb = lds + ((NT - 2) % 3) * 32768;
#pragma unroll
    for (int i = 0; i < 4; ++i) {
      av[i] = *(const bf16x8*)(sb + acore + i * 1024);
      bv[i] = *(const bf16x8*)(sb + bcore + i * 1024);
    }
    WAITL0;
#pragma unroll
    for (int mi = 0; mi < 4; ++mi)
#pragma unroll
      for (int ni = 0; ni < 4; ++ni)
        acc[mi][ni] = __builtin_amdgcn_mfma_f32_16x16x32_bf16(
            av[mi], bv[ni], acc[mi][ni], 0, 0, 0);
    WAITV(0);  // tile NT-1's loads retired
    SBAR;
  }
  // tail tt = NT-1
  {
    const char* sb = lds + ((NT - 1) % 3) * 32768;
#pragma unroll
    for (int i = 0; i < 4; ++i) {
      av[i] = *(const bf16x8*)(sb + acore + i * 1024);
      bv[i] = *(const bf16x8*)(sb + bcore + i * 1024);
    }
    WAITL0;
#pragma unroll
    for (int mi = 0; mi < 4; ++mi)
#pragma unroll
      for (int ni = 0; ni < 4; ++ni)
        acc[mi][ni] = __builtin_amdgcn_mfma_f32_16x16x32_bf16(
            av[mi], bv[ni], acc[mi][ni], 0, 0, 0);
  }

  // ===== coalesced epilogue (R12) =====
  // acc layout: col = lane&15, row = (lane>>4)*4 + j [m89-verified].
  // Chunk mi: 64 rows (4 waves' 16-row slices) x 256 cols through LDS.
  SBAR;  // everyone done reading K-loop LDS -> reclaim for epilogue
  const float* nrmz = (MODE == 4) ? (norm + z * normOffZ) : nullptr;
  float* Cf = (float*)C + z * cOffZ;
  unsigned short* Cu = (unsigned short*)C + z * cOffZ;
  const bool lower = (m0 < 1024);  // block-uniform (MODE 1: KpT vs VT half)
#pragma unroll
  for (int mi = 0; mi < 4; ++mi) {
    const int rbase = m0 + wm * 64 + mi * 16 + fq * 4;  // global row (j=0)
#pragma unroll
    for (int ni = 0; ni < 4; ++ni) {
      const int c = n0 + wn * 64 + ni * 16 + fr;  // global col
      float cb = 0.f;
      if (MODE == 0) cb = bias[c];
#pragma unroll
      for (int j = 0; j < 4; ++j) {
        float v = acc[mi][ni][j];
        if (MODE == 0) v += cb;
        if (MODE == 1) v += lower ? bias[rbase + j] : bias2[rbase - 1024 + j];
        if (MODE == 0 || (MODE == 1 && lower))
          v = (v > 0.f) ? v + 1.f : __expf(v);
        const int r = wm * 16 + fq * 4 + j;      // chunk row 0..63
        const int col = wn * 64 + ni * 16 + fr;  // chunk col 0..255
        if (MODE == 4) {
          v = v / nrmz[rbase + j];
          const int lg = r * 1024 + col * 4;
          *(float*)(lds + (lg ^ ((r & 7) << 6))) = v;
        } else {
          const int lg = r * 512 + col * 2;
          *(unsigned short*)(lds + (lg ^ ((r & 7) << 5))) = f2bf(v);
        }
      }
    }
    SBAR;  // chunk filled
    {
      const int r = t >> 4;  // 0..63
      const long long grow = m0 + (r >> 4) * 64 + mi * 16 + (r & 15);
      if (MODE == 4) {
        const char* src = lds + ((r * 1024 + (t & 15) * 64) ^ ((r & 7) << 6));
        float* dst = Cf + grow * ldc + n0 + (t & 15) * 16;
        f32x4 a0 = *(const f32x4*)(src);
        f32x4 a1 = *(const f32x4*)(src + 16);
        f32x4 a2 = *(const f32x4*)(src + 32);
        f32x4 a3 = *(const f32x4*)(src + 48);
        *(f32x4*)(dst) = a0;
        *(f32x4*)(dst + 4) = a1;
        *(f32x4*)(dst + 8) = a2;
        *(f32x4*)(dst + 12) = a3;
      } else {
        const char* src = lds + ((r * 512 + (t & 15) * 32) ^ ((r & 7) << 5));
        unsigned short* dst = Cu + grow * ldc + n0 + (t & 15) * 16;
        u16x8 a0 = *(const u16x8*)(src);
        u16x8 a1 = *(const u16x8*)(src + 16);
        *(u16x8*)(dst) = a0;
        *(u16x8*)(dst + 8) = a1;
      }
    }
    SBAR;  // chunk drained -> LDS reusable for next chunk
  }
}

// KVt[b][e][d] = sum_ks P[ks*4+b][e][d]   (P: [16][1024][1024] bf16 partials)
__global__ __launch_bounds__(256) void reduce_kvt(
    const unsigned short* __restrict__ P, unsigned short* __restrict__ KVt) {
  const long long i = ((long long)blockIdx.x * 256 + threadIdx.x) * 8;
  const int b = (int)(i >> 20);
  const long long ed = i & ((1ll << 20) - 1);
  float s[8] = {0.f, 0.f, 0.f, 0.f, 0.f, 0.f, 0.f, 0.f};
#pragma unroll
  for (int ks = 0; ks < 4; ++ks) {
    u16x8 v = *(const u16x8*)(P + ((long long)(ks * 4 + b) << 20) + ed);
#pragma unroll
    for (int j = 0; j < 8; ++j) s[j] += bf2f(v[j]);
  }
  u16x8 o;
#pragma unroll
  for (int j = 0; j < 8; ++j) o[j] = f2bf(s[j]);
  *(u16x8*)(KVt + i) = o;
}

// W [1024(in)][1024(out)] f32  ->  WT [1024(out)][1024(in)] bf16
__global__ __launch_bounds__(256) void transpose_w(
    const float* __restrict__ W, unsigned short* __restrict__ WT) {
  __shared__ float tile[32][33];
  const int tx = threadIdx.x & 31, ty = threadIdx.x >> 5;
  const int i0 = blockIdx.y * 32, o0 = blockIdx.x * 32;
#pragma unroll
  for (int s = 0; s < 32; s += 8)
    tile[ty + s][tx] = W[(long long)(i0 + ty + s) * 1024 + o0 + tx];
  __syncthreads();
#pragma unroll
  for (int s = 0; s < 32; s += 8)
    WT[(long long)(o0 + ty + s) * 1024 + i0 + tx] = f2bf(tile[tx][ty + s]);
}

__global__ __launch_bounds__(256) void convert_x(
    const float4* __restrict__ in, uint2* __restrict__ out, int n4) {
  const int stride = gridDim.x * blockDim.x;
  for (int i = blockIdx.x * blockDim.x + threadIdx.x; i < n4; i += stride) {
    float4 v = in[i];
    uint2 o;
    o.x = (unsigned)f2bf(v.x) | ((unsigned)f2bf(v.y) << 16);
    o.y = (unsigned)f2bf(v.z) | ((unsigned)f2bf(v.w) << 16);
    out[i] = o;
  }
}

// K_sum[b][d] = sum_n KpT[d][b*4096 + n]   (one wave per (b,d), u16x8 loads)
__global__ __launch_bounds__(256) void ksum_kernel(
    const unsigned short* __restrict__ KpT, float* __restrict__ Ksum) {
  const int gw = (blockIdx.x * 256 + threadIdx.x) >> 6;  // 0..4095
  const int lane = threadIdx.x & 63;
  const int d = gw >> 2, b = gw & 3;
  const unsigned short* p = KpT + (long long)d * 16384 + b * 4096 + lane * 8;
  float s = 0.f;
#pragma unroll
  for (int it = 0; it < 8; ++it) {
    u16x8 v = *(const u16x8*)(p + it * 512);
#pragma unroll
    for (int j = 0; j < 8; ++j) s += bf2f(v[j]);
  }
#pragma unroll
  for (int o = 32; o > 0; o >>= 1) s += __shfl_down(s, o, 64);
  if (lane == 0) Ksum[b * 1024 + d] = s;
}

// nrm[m] = eps + sum_d Qp[m][d] * Ksum[b][d]   (one wave per row m)
__global__ __launch_bounds__(256) void norm_kernel(
    const unsigned short* __restrict__ Qp, const float* __restrict__ Ksum,
    float* __restrict__ nrm) {
  const int gw = (blockIdx.x * 256 + threadIdx.x) >> 6;  // 0..16383
  const int lane = threadIdx.x & 63;
  const int b = gw >> 12;
  const unsigned short* q = Qp + (long long)gw * 1024 + lane * 8;
  const float* ks = Ksum + b * 1024 + lane * 8;
  float s = 0.f;
#pragma unroll
  for (int it = 0; it < 2; ++it) {
    u16x8 v = *(const u16x8*)(q + it * 512);
    float4 k0 = *(const float4*)(ks + it * 512);
    float4 k1 = *(const float4*)(ks + it * 512 + 4);
    s += bf2f(v[0]) * k0.x + bf2f(v[1]) * k0.y + bf2f(v[2]) * k0.z +
         bf2f(v[3]) * k0.w + bf2f(v[4]) * k1.x + bf2f(v[5]) * k1.y +
         bf2f(v[6]) * k1.z + bf2f(v[7]) * k1.w;
  }
#pragma unroll
  for (int o = 32; o > 0; o >>= 1) s += __shfl_down(s, o, 64);
  if (lane == 0) nrm[gw] = s + 1e-6f;
}

extern "C" void kernel_launch(void* const* d_in, const int* in_sizes, int n_in,
                              void* d_out, int out_size, void* d_ws,
                              size_t ws_size, hipStream_t stream) {
  const float* x  = (const float*)d_in[0];
  const float* Wq = (const float*)d_in[1];
  const float* bq = (const float*)d_in[2];
  const float* Wk = (const float*)d_in[3];
  const float* bk = (const float*)d_in[4];
  const float* Wv = (const float*)d_in[5];
  const float* bv = (const float*)d_in[6];
  float* out = (float*)d_out;

  const size_t MN = 16384ull * 1024ull;  // B*N*D elements
  char* w = (char*)d_ws;
  unsigned short* xb  = (unsigned short*)w;  w += MN * 2;                 // x bf16; dead after projections -> KVt partials [16][1024][1024]
  unsigned short* WT  = (unsigned short*)w;  w += 3ull * 1024 * 1024 * 2; // WqT|WkT|WvT bf16
  unsigned short* Qp  = (unsigned short*)w;  w += MN * 2;                 // [16384][1024]
  unsigned short* KVb = (unsigned short*)w;  w += 2 * MN * 2;            // [2048][16384]: rows 0-1023 KpT, 1024-2047 VT
  unsigned short* KVt = (unsigned short*)w;  w += 4ull * 1024 * 1024 * 2; // [4][1024(e)][1024(d)]
  float* Ksum = (float*)w;  w += 4ull * 1024 * 4;                         // [4][1024]
  float* nrm  = (float*)w;  w += 16384ull * 4;                            // [16384]
  unsigned short* Pkv = xb;  // split-K KVt partials, aliases dead xb
  unsigned short* KpT = KVb;
  unsigned short* VT  = KVb + MN;

  transpose_w<<<dim3(32, 32), 256, 0, stream>>>(Wq, WT);
  transpose_w<<<dim3(32, 32), 256, 0, stream>>>(Wk, WT + 1024 * 1024);
  transpose_w<<<dim3(32, 32), 256, 0, stream>>>(Wv, WT + 2 * 1024 * 1024);
  convert_x<<<2048, 256, 0, stream>>>((const float4*)x, (uint2*)xb,
                                      (int)(MN / 4));

  // Qp = elu(x @ Wq + bq)+1 : A=xb[16384][1024], Bt=WqT[1024][1024]
  gemm256w<0><<<dim3(4, 64, 1), 1024, 0, stream>>>(
      xb, 1024, 0, WT, 1024, 0, Qp, 1024, 0, bq, nullptr, nullptr, 0, 1024);
  // merged K/V projection: A=[WkT;WvT][2048][1024], Bt=xb[16384][1024]
  //   rows <1024: KpT = elu(.+bk)+1 ; rows >=1024: VT = . + bv
  gemm256w<1><<<dim3(64, 8, 1), 1024, 0, stream>>>(
      WT + 1024 * 1024, 1024, 0, xb, 1024, 0, KVb, 16384, 0, bk, bv, nullptr,
      0, 1024);
  ksum_kernel<<<1024, 256, 0, stream>>>(KpT, Ksum);
  // split-K KVt partials: z = ks*4+b; P[z] = VT[:,win] . KpT[:,win]^T
  gemm256w<3><<<dim3(4, 4, 16), 1024, 0, stream>>>(
      VT, 16384, 0, KpT, 16384, 0, Pkv, 1024, 1024 * 1024, nullptr, nullptr,
      nullptr, 0, 1024);
  reduce_kvt<<<2048, 256, 0, stream>>>(Pkv, KVt);
  norm_kernel<<<4096, 256, 0, stream>>>(Qp, Ksum, nrm);
  // out[b][n][e] = (sum_d Qp[bn][d] * KVt[b][e][d]) / nrm[bn]
  gemm256w<4><<<dim3(4, 16, 4), 1024, 0, stream>>>(
      Qp, 1024, 4096ll * 1024, KVt, 1024, 1024 * 1024, out, 1024,
      4096ll * 1024, nullptr, nullptr, nrm, 4096, 1024);
}

// Round 13
// 244.432 us; speedup vs baseline: 1.1150x; 1.1150x over previous
//
#include <hip/hip_runtime.h>
#include <hip/hip_bf16.h>
#include <cstdint>

typedef __bf16 bf16x8 __attribute__((ext_vector_type(8)));
typedef float  f32x4  __attribute__((ext_vector_type(4)));
typedef unsigned short u16x8 __attribute__((ext_vector_type(8)));

__device__ __forceinline__ unsigned short f2bf(float f) {
  __hip_bfloat16 h = __float2bfloat16(f);
  return __builtin_bit_cast(unsigned short, h);
}
__device__ __forceinline__ float bf2f(unsigned short u) {
  return __builtin_bit_cast(float, (unsigned)u << 16);
}

#define GL2LDS16(gp, lp)                                                      \
  __builtin_amdgcn_global_load_lds(                                           \
      (const __attribute__((address_space(1))) unsigned int*)(gp),            \
      (__attribute__((address_space(3))) unsigned int*)(lp), 16, 0, 0)

#define SBAR                                                                  \
  {                                                                           \
    __builtin_amdgcn_s_barrier();                                             \
    __builtin_amdgcn_sched_barrier(0);                                        \
  }
#define WAITV(n)                                                              \
  {                                                                           \
    asm volatile("s_waitcnt vmcnt(" #n ")" ::: "memory");                     \
    __builtin_amdgcn_sched_barrier(0);                                        \
  }
#define WAITL0                                                                \
  {                                                                           \
    asm volatile("s_waitcnt lgkmcnt(0)" ::: "memory");                        \
    __builtin_amdgcn_sched_barrier(0);                                        \
  }

// ============ Kernel A: R9-measured-best (16 waves, BK=32, 3-slot ring) =====
// 256x256 tile, C[m][n] = sum_k A[m][k]*B[n][k]. Per-wave 64x64 (4Mx4N).
// 96KB LDS ring, launch_bounds(1024,4) -> 64 VGPR (R10: (1024,8) forces 32
// VGPR + catastrophic spill; never again). Single-barrier counted-vmcnt loop.
// Best measured for: Qp (mode 0), merged KV-proj (mode 1), split-K (mode 3).
// R12 coalesced epilogue reverted (WRITE dropped 113->69MB but dur flat ->
// write-amp exonerated; direct epilogue restored).
// Swizzle phys = l ^ (((l>>7)&3)<<4) on BOTH pre-swizzled global source and
// ds_read address (involution; 0 bank conflicts measured).
template <int MODE>
__global__ __launch_bounds__(1024, 4) void gemm256w(
    const unsigned short* __restrict__ A, long long lda, long long aOffZ,
    const unsigned short* __restrict__ B, long long ldb, long long bOffZ,
    void* __restrict__ C, long long ldc, long long cOffZ,
    const float* __restrict__ bias, const float* __restrict__ bias2,
    int K) {
  __shared__ __attribute__((aligned(16))) char lds[3 * 32768];
  const int t = threadIdx.x;
  const int wave = t >> 6, lane = t & 63;
  const int wm = wave >> 2, wn = wave & 3;
  const int fr = lane & 15, fq = lane >> 4;

  const int gx = gridDim.x, gy = gridDim.y;
  int flat = blockIdx.y * gx + blockIdx.x;
  const int total = gx * gy;
  if ((total & 7) == 0) flat = (flat & 7) * (total >> 3) + (flat >> 3);
  int bx, by;
  if (MODE == 1) {  // column-stripes per XCD: whole A stays L2-resident
    bx = flat / gy;
    by = flat - bx * gy;
  } else {
    bx = flat % gx;
    by = flat / gx;
  }
  const int m0 = by * 256, n0 = bx * 256;

  const long long z = blockIdx.z;
  long long aBase, bBase;
  if (MODE == 3) {
    const long long koff = (z & 3) * 4096 + (z >> 2) * 1024;
    aBase = koff;
    bBase = koff;
  } else {
    aBase = z * aOffZ;
    bBase = z * bOffZ;
  }
  const unsigned short* Az = A + aBase;
  const unsigned short* Bz = B + bBase;

  const unsigned short* gA;
  const unsigned short* gB;
  {
    int d = t * 16;
    int l = d ^ (((d >> 7) & 3) << 4);
    int row = l >> 6, kel = (l & 63) >> 1;
    gA = Az + (long long)(m0 + row) * lda + kel;
    gB = Bz + (long long)(n0 + row) * ldb + kel;
  }

  const int slotx = (fr >> 1) & 3;
  const int acore = wm * 4096 + fr * 64 + ((fq ^ slotx) << 4);
  const int bcore = 16384 + wn * 4096 + fr * 64 + ((fq ^ slotx) << 4);

  f32x4 acc[4][4];
#pragma unroll
  for (int i = 0; i < 4; ++i)
#pragma unroll
    for (int j = 0; j < 4; ++j) acc[i][j] = (f32x4){0.f, 0.f, 0.f, 0.f};

  const int NT = K >> 5;

  auto stage = [&](int tile) {
    char* sb = lds + (tile % 3) * 32768 + wave * 1024;
    const int k0 = tile << 5;
    GL2LDS16(gA + k0, sb);
    GL2LDS16(gB + k0, sb + 16384);
  };

  stage(0);
  stage(1);
  WAITV(2);
  SBAR;

  bf16x8 av[4], bv[4];
  for (int tt = 0; tt < NT - 2; ++tt) {
    const char* sb = lds + (tt % 3) * 32768;
    stage(tt + 2);
#pragma unroll
    for (int i = 0; i < 4; ++i) {
      av[i] = *(const bf16x8*)(sb + acore + i * 1024);
      bv[i] = *(const bf16x8*)(sb + bcore + i * 1024);
    }
    WAITL0;
    __builtin_amdgcn_s_setprio(1);
#pragma unroll
    for (int mi = 0; mi < 4; ++mi)
#pragma unroll
      for (int ni = 0; ni < 4; ++ni)
        acc[mi][ni] = __builtin_amdgcn_mfma_f32_16x16x32_bf16(
            av[mi], bv[ni], acc[mi][ni], 0, 0, 0);
    __builtin_amdgcn_s_setprio(0);
    WAITV(2);
    SBAR;
  }
  {
    const char* sb = lds + ((NT - 2) % 3) * 32768;
#pragma unroll
    for (int i = 0; i < 4; ++i) {
      av[i] = *(const bf16x8*)(sb + acore + i * 1024);
      bv[i] = *(const bf16x8*)(sb + bcore + i * 1024);
    }
    WAITL0;
#pragma unroll
    for (int mi = 0; mi < 4; ++mi)
#pragma unroll
      for (int ni = 0; ni < 4; ++ni)
        acc[mi][ni] = __builtin_amdgcn_mfma_f32_16x16x32_bf16(
            av[mi], bv[ni], acc[mi][ni], 0, 0, 0);
    WAITV(0);
    SBAR;
  }
  {
    const char* sb = lds + ((NT - 1) % 3) * 32768;
#pragma unroll
    for (int i = 0; i < 4; ++i) {
      av[i] = *(const bf16x8*)(sb + acore + i * 1024);
      bv[i] = *(const bf16x8*)(sb + bcore + i * 1024);
    }
    WAITL0;
#pragma unroll
    for (int mi = 0; mi < 4; ++mi)
#pragma unroll
      for (int ni = 0; ni < 4; ++ni)
        acc[mi][ni] = __builtin_amdgcn_mfma_f32_16x16x32_bf16(
            av[mi], bv[ni], acc[mi][ni], 0, 0, 0);
  }

  // direct epilogue. C/D: col = lane&15, row = (lane>>4)*4 + j [m89]
  unsigned short* Cu = (unsigned short*)C + z * cOffZ;
  const bool lower = (m0 < 1024);
#pragma unroll
  for (int mi = 0; mi < 4; ++mi) {
    const int rbase = m0 + wm * 64 + mi * 16 + fq * 4;
    float rb[4];
#pragma unroll
    for (int j = 0; j < 4; ++j)
      if (MODE == 1) rb[j] = lower ? bias[rbase + j] : bias2[rbase - 1024 + j];
#pragma unroll
    for (int ni = 0; ni < 4; ++ni) {
      const int c = n0 + wn * 64 + ni * 16 + fr;
      float cb = 0.f;
      if (MODE == 0) cb = bias[c];
#pragma unroll
      for (int j = 0; j < 4; ++j) {
        float v = acc[mi][ni][j];
        if (MODE == 0) v += cb;
        if (MODE == 1) v += rb[j];
        if (MODE == 0 || (MODE == 1 && lower))
          v = (v > 0.f) ? v + 1.f : __expf(v);
        Cu[(long long)(rbase + j) * ldc + c] = f2bf(v);
      }
    }
  }
}

// ===== Kernel B: R7-measured-best for the numerator (8 waves, BK=64, =====
// 4-phase counted-vmcnt, 2x64KB LDS). Measured 73us on this exact shape
// (R7 top dispatch, refcheck-passed). out = (Qp . KVt^T) / nrm, f32.
__global__ __launch_bounds__(512, 2) void gemm_num(
    const unsigned short* __restrict__ A, long long aOffZ,
    const unsigned short* __restrict__ B, long long bOffZ,
    float* __restrict__ C, long long cOffZ,
    const float* __restrict__ norm, long long normOffZ) {
  const long long lda = 1024, ldb = 1024, ldc = 1024;
  const int K = 1024;
  __shared__ __attribute__((aligned(16))) char lds[2 * 65536];
  const int t = threadIdx.x;
  const int wave = t >> 6, lane = t & 63;
  const int wm = wave >> 2, wn = wave & 3;
  const int fr = lane & 15, fq = lane >> 4;

  const int gx = gridDim.x, gy = gridDim.y;
  int flat = blockIdx.y * gx + blockIdx.x;
  const int total = gx * gy;
  if ((total & 7) == 0) flat = (flat & 7) * (total >> 3) + (flat >> 3);
  const int bx = flat % gx, by = flat / gx;
  const int m0 = by * 256, n0 = bx * 256;

  const long long z = blockIdx.z;
  const unsigned short* Az = A + z * aOffZ;
  const unsigned short* Bz = B + z * bOffZ;

  const unsigned short* gA[2];
  const unsigned short* gB[2];
#pragma unroll
  for (int c = 0; c < 2; ++c) {
    int d = c * 8192 + t * 16;
    int l = d ^ (((d >> 7) & 3) << 4);
    int row = l >> 6, kel = (l & 63) >> 1;
    gA[c] = Az + (long long)(m0 + row) * lda + kel;
    gB[c] = Bz + (long long)(n0 + row) * ldb + kel;
  }

  const int slotx = (fr >> 1) & 3;
  const int acore = wm * 8192 + fr * 64 + ((fq ^ slotx) << 4);
  const int bcore = wn * 4096 + fr * 64 + ((fq ^ slotx) << 4);

  f32x4 acc[8][4];
#pragma unroll
  for (int i = 0; i < 8; ++i)
#pragma unroll
    for (int j = 0; j < 4; ++j) acc[i][j] = (f32x4){0.f, 0.f, 0.f, 0.f};

  const int NT = K >> 6;

  auto stage_sub = [&](int tile, int which) {
    char* dst = lds + (tile & 1) * 65536 + which * 16384 + wave * 1024;
    const int kofs = (tile << 6) + ((which >> 1) << 5);
    if (which & 1) {
      GL2LDS16(gB[0] + kofs, dst);
      GL2LDS16(gB[1] + kofs, dst + 8192);
    } else {
      GL2LDS16(gA[0] + kofs, dst);
      GL2LDS16(gA[1] + kofs, dst + 8192);
    }
  };

  stage_sub(0, 0);
  stage_sub(0, 1);
  stage_sub(0, 2);
  stage_sub(0, 3);
  WAITV(4);
  SBAR;

  bf16x8 av[4], bv0[4], bv1[4];
  for (int tt = 0; tt < NT - 1; ++tt) {
    const char* bufp = lds + (tt & 1) * 65536;
    // P1
#pragma unroll
    for (int i = 0; i < 4; ++i) {
      av[i] = *(const bf16x8*)(bufp + acore + i * 1024);
      bv0[i] = *(const bf16x8*)(bufp + 16384 + bcore + i * 1024);
    }
    stage_sub(tt + 1, 0);
    SBAR;
    WAITL0;
    __builtin_amdgcn_s_setprio(1);
#pragma unroll
    for (int mi = 0; mi < 4; ++mi)
#pragma unroll
      for (int ni = 0; ni < 4; ++ni)
        acc[mi][ni] = __builtin_amdgcn_mfma_f32_16x16x32_bf16(
            av[mi], bv0[ni], acc[mi][ni], 0, 0, 0);
    __builtin_amdgcn_s_setprio(0);
    SBAR;
    // P2
#pragma unroll
    for (int i = 0; i < 4; ++i)
      av[i] = *(const bf16x8*)(bufp + acore + (4 + i) * 1024);
    stage_sub(tt + 1, 1);
    SBAR;
    WAITL0;
    __builtin_amdgcn_s_setprio(1);
#pragma unroll
    for (int mi = 0; mi < 4; ++mi)
#pragma unroll
      for (int ni = 0; ni < 4; ++ni)
        acc[4 + mi][ni] = __builtin_amdgcn_mfma_f32_16x16x32_bf16(
            av[mi], bv0[ni], acc[4 + mi][ni], 0, 0, 0);
    __builtin_amdgcn_s_setprio(0);
    WAITV(4);
    SBAR;
    // P3
#pragma unroll
    for (int i = 0; i < 4; ++i) {
      av[i] = *(const bf16x8*)(bufp + 32768 + acore + i * 1024);
      bv1[i] = *(const bf16x8*)(bufp + 49152 + bcore + i * 1024);
    }
    stage_sub(tt + 1, 2);
    SBAR;
    WAITL0;
    __builtin_amdgcn_s_setprio(1);
#pragma unroll
    for (int mi = 0; mi < 4; ++mi)
#pragma unroll
      for (int ni = 0; ni < 4; ++ni)
        acc[mi][ni] = __builtin_amdgcn_mfma_f32_16x16x32_bf16(
            av[mi], bv1[ni], acc[mi][ni], 0, 0, 0);
    __builtin_amdgcn_s_setprio(0);
    SBAR;
    // P4
#pragma unroll
    for (int i = 0; i < 4; ++i)
      av[i] = *(const bf16x8*)(bufp + 32768 + acore + (4 + i) * 1024);
    stage_sub(tt + 1, 3);
    SBAR;
    WAITL0;
    __builtin_amdgcn_s_setprio(1);
#pragma unroll
    for (int mi = 0; mi < 4; ++mi)
#pragma unroll
      for (int ni = 0; ni < 4; ++ni)
        acc[4 + mi][ni] = __builtin_amdgcn_mfma_f32_16x16x32_bf16(
            av[mi], bv1[ni], acc[4 + mi][ni], 0, 0, 0);
    __builtin_amdgcn_s_setprio(0);
    WAITV(4);
    SBAR;
  }
  {
    const char* bufp = lds + ((NT - 1) & 1) * 65536;
#pragma unroll
    for (int i = 0; i < 4; ++i) {
      av[i] = *(const bf16x8*)(bufp + acore + i * 1024);
      bv0[i] = *(const bf16x8*)(bufp + 16384 + bcore + i * 1024);
    }
    SBAR;
    WAITL0;
#pragma unroll
    for (int mi = 0; mi < 4; ++mi)
#pragma unroll
      for (int ni = 0; ni < 4; ++ni)
        acc[mi][ni] = __builtin_amdgcn_mfma_f32_16x16x32_bf16(
            av[mi], bv0[ni], acc[mi][ni], 0, 0, 0);
    SBAR;
#pragma unroll
    for (int i = 0; i < 4; ++i)
      av[i] = *(const bf16x8*)(bufp + acore + (4 + i) * 1024);
    SBAR;
    WAITL0;
#pragma unroll
    for (int mi = 0; mi < 4; ++mi)
#pragma unroll
      for (int ni = 0; ni < 4; ++ni)
        acc[4 + mi][ni] = __builtin_amdgcn_mfma_f32_16x16x32_bf16(
            av[mi], bv0[ni], acc[4 + mi][ni], 0, 0, 0);
    WAITV(0);
    SBAR;
#pragma unroll
    for (int i = 0; i < 4; ++i) {
      av[i] = *(const bf16x8*)(bufp + 32768 + acore + i * 1024);
      bv1[i] = *(const bf16x8*)(bufp + 49152 + bcore + i * 1024);
    }
    WAITL0;
#pragma unroll
    for (int mi = 0; mi < 4; ++mi)
#pragma unroll
      for (int ni = 0; ni < 4; ++ni)
        acc[mi][ni] = __builtin_amdgcn_mfma_f32_16x16x32_bf16(
            av[mi], bv1[ni], acc[mi][ni], 0, 0, 0);
#pragma unroll
    for (int i = 0; i < 4; ++i)
      av[i] = *(const bf16x8*)(bufp + 32768 + acore + (4 + i) * 1024);
    WAITL0;
#pragma unroll
    for (int mi = 0; mi < 4; ++mi)
#pragma unroll
      for (int ni = 0; ni < 4; ++ni)
        acc[4 + mi][ni] = __builtin_amdgcn_mfma_f32_16x16x32_bf16(
            av[mi], bv1[ni], acc[4 + mi][ni], 0, 0, 0);
  }

  const float* nrmz = norm + z * normOffZ;
  float* Cf = C + z * cOffZ;
#pragma unroll
  for (int mi = 0; mi < 8; ++mi) {
    const int rbase = m0 + wm * 128 + mi * 16 + fq * 4;
    float nv[4];
#pragma unroll
    for (int j = 0; j < 4; ++j) nv[j] = nrmz[rbase + j];
#pragma unroll
    for (int ni = 0; ni < 4; ++ni) {
      const int c = n0 + wn * 64 + ni * 16 + fr;
#pragma unroll
      for (int j = 0; j < 4; ++j)
        Cf[(long long)(rbase + j) * ldc + c] = acc[mi][ni][j] / nv[j];
    }
  }
}

// KVt[b][e][d] = sum_ks P[ks*4+b][e][d]
__global__ __launch_bounds__(256) void reduce_kvt(
    const unsigned short* __restrict__ P, unsigned short* __restrict__ KVt) {
  const long long i = ((long long)blockIdx.x * 256 + threadIdx.x) * 8;
  const int b = (int)(i >> 20);
  const long long ed = i & ((1ll << 20) - 1);
  float s[8] = {0.f, 0.f, 0.f, 0.f, 0.f, 0.f, 0.f, 0.f};
#pragma unroll
  for (int ks = 0; ks < 4; ++ks) {
    u16x8 v = *(const u16x8*)(P + ((long long)(ks * 4 + b) << 20) + ed);
#pragma unroll
    for (int j = 0; j < 8; ++j) s[j] += bf2f(v[j]);
  }
  u16x8 o;
#pragma unroll
  for (int j = 0; j < 8; ++j) o[j] = f2bf(s[j]);
  *(u16x8*)(KVt + i) = o;
}

__global__ __launch_bounds__(256) void transpose_w(
    const float* __restrict__ W, unsigned short* __restrict__ WT) {
  __shared__ float tile[32][33];
  const int tx = threadIdx.x & 31, ty = threadIdx.x >> 5;
  const int i0 = blockIdx.y * 32, o0 = blockIdx.x * 32;
#pragma unroll
  for (int s = 0; s < 32; s += 8)
    tile[ty + s][tx] = W[(long long)(i0 + ty + s) * 1024 + o0 + tx];
  __syncthreads();
#pragma unroll
  for (int s = 0; s < 32; s += 8)
    WT[(long long)(o0 + ty + s) * 1024 + i0 + tx] = f2bf(tile[tx][ty + s]);
}

__global__ __launch_bounds__(256) void convert_x(
    const float4* __restrict__ in, uint2* __restrict__ out, int n4) {
  const int stride = gridDim.x * blockDim.x;
  for (int i = blockIdx.x * blockDim.x + threadIdx.x; i < n4; i += stride) {
    float4 v = in[i];
    uint2 o;
    o.x = (unsigned)f2bf(v.x) | ((unsigned)f2bf(v.y) << 16);
    o.y = (unsigned)f2bf(v.z) | ((unsigned)f2bf(v.w) << 16);
    out[i] = o;
  }
}

__global__ __launch_bounds__(256) void ksum_kernel(
    const unsigned short* __restrict__ KpT, float* __restrict__ Ksum) {
  const int gw = (blockIdx.x * 256 + threadIdx.x) >> 6;
  const int lane = threadIdx.x & 63;
  const int d = gw >> 2, b = gw & 3;
  const unsigned short* p = KpT + (long long)d * 16384 + b * 4096 + lane * 8;
  float s = 0.f;
#pragma unroll
  for (int it = 0; it < 8; ++it) {
    u16x8 v = *(const u16x8*)(p + it * 512);
#pragma unroll
    for (int j = 0; j < 8; ++j) s += bf2f(v[j]);
  }
#pragma unroll
  for (int o = 32; o > 0; o >>= 1) s += __shfl_down(s, o, 64);
  if (lane == 0) Ksum[b * 1024 + d] = s;
}

__global__ __launch_bounds__(256) void norm_kernel(
    const unsigned short* __restrict__ Qp, const float* __restrict__ Ksum,
    float* __restrict__ nrm) {
  const int gw = (blockIdx.x * 256 + threadIdx.x) >> 6;
  const int lane = threadIdx.x & 63;
  const int b = gw >> 12;
  const unsigned short* q = Qp + (long long)gw * 1024 + lane * 8;
  const float* ks = Ksum + b * 1024 + lane * 8;
  float s = 0.f;
#pragma unroll
  for (int it = 0; it < 2; ++it) {
    u16x8 v = *(const u16x8*)(q + it * 512);
    float4 k0 = *(const float4*)(ks + it * 512);
    float4 k1 = *(const float4*)(ks + it * 512 + 4);
    s += bf2f(v[0]) * k0.x + bf2f(v[1]) * k0.y + bf2f(v[2]) * k0.z +
         bf2f(v[3]) * k0.w + bf2f(v[4]) * k1.x + bf2f(v[5]) * k1.y +
         bf2f(v[6]) * k1.z + bf2f(v[7]) * k1.w;
  }
#pragma unroll
  for (int o = 32; o > 0; o >>= 1) s += __shfl_down(s, o, 64);
  if (lane == 0) nrm[gw] = s + 1e-6f;
}

extern "C" void kernel_launch(void* const* d_in, const int* in_sizes, int n_in,
                              void* d_out, int out_size, void* d_ws,
                              size_t ws_size, hipStream_t stream) {
  const float* x  = (const float*)d_in[0];
  const float* Wq = (const float*)d_in[1];
  const float* bq = (const float*)d_in[2];
  const float* Wk = (const float*)d_in[3];
  const float* bk = (const float*)d_in[4];
  const float* Wv = (const float*)d_in[5];
  const float* bv = (const float*)d_in[6];
  float* out = (float*)d_out;

  const size_t MN = 16384ull * 1024ull;
  char* w = (char*)d_ws;
  unsigned short* xb  = (unsigned short*)w;  w += MN * 2;
  unsigned short* WT  = (unsigned short*)w;  w += 3ull * 1024 * 1024 * 2;
  unsigned short* Qp  = (unsigned short*)w;  w += MN * 2;
  unsigned short* KVb = (unsigned short*)w;  w += 2 * MN * 2;
  unsigned short* KVt = (unsigned short*)w;  w += 4ull * 1024 * 1024 * 2;
  float* Ksum = (float*)w;  w += 4ull * 1024 * 4;
  float* nrm  = (float*)w;  w += 16384ull * 4;
  unsigned short* Pkv = xb;  // split-K partials alias dead xb
  unsigned short* KpT = KVb;
  unsigned short* VT  = KVb + MN;

  transpose_w<<<dim3(32, 32), 256, 0, stream>>>(Wq, WT);
  transpose_w<<<dim3(32, 32), 256, 0, stream>>>(Wk, WT + 1024 * 1024);
  transpose_w<<<dim3(32, 32), 256, 0, stream>>>(Wv, WT + 2 * 1024 * 1024);
  convert_x<<<2048, 256, 0, stream>>>((const float4*)x, (uint2*)xb,
                                      (int)(MN / 4));

  // Qp = elu(x @ Wq + bq)+1
  gemm256w<0><<<dim3(4, 64, 1), 1024, 0, stream>>>(
      xb, 1024, 0, WT, 1024, 0, Qp, 1024, 0, bq, nullptr, 1024);
  // merged K/V projection
  gemm256w<1><<<dim3(64, 8, 1), 1024, 0, stream>>>(
      WT + 1024 * 1024, 1024, 0, xb, 1024, 0, KVb, 16384, 0, bk, bv, 1024);
  ksum_kernel<<<1024, 256, 0, stream>>>(KpT, Ksum);
  // split-K KVt partials
  gemm256w<3><<<dim3(4, 4, 16), 1024, 0, stream>>>(
      VT, 16384, 0, KpT, 16384, 0, Pkv, 1024, 1024 * 1024, nullptr, nullptr,
      1024);
  reduce_kvt<<<2048, 256, 0, stream>>>(Pkv, KVt);
  norm_kernel<<<4096, 256, 0, stream>>>(Qp, Ksum, nrm);
  // numerator via R7-best 8-wave 4-phase kernel
  gemm_num<<<dim3(4, 16, 4), 512, 0, stream>>>(
      Qp, 4096ll * 1024, KVt, 1024 * 1024, out, 4096ll * 1024, nrm, 4096);
}

// Round 14
// 238.496 us; speedup vs baseline: 1.1428x; 1.0249x over previous
//
#include <hip/hip_runtime.h>
#include <hip/hip_bf16.h>
#include <cstdint>

typedef __bf16 bf16x8 __attribute__((ext_vector_type(8)));
typedef float  f32x4  __attribute__((ext_vector_type(4)));
typedef unsigned short u16x8 __attribute__((ext_vector_type(8)));

__device__ __forceinline__ unsigned short f2bf(float f) {
  __hip_bfloat16 h = __float2bfloat16(f);
  return __builtin_bit_cast(unsigned short, h);
}
__device__ __forceinline__ float bf2f(unsigned short u) {
  return __builtin_bit_cast(float, (unsigned)u << 16);
}

#define GL2LDS16(gp, lp)                                                      \
  __builtin_amdgcn_global_load_lds(                                           \
      (const __attribute__((address_space(1))) unsigned int*)(gp),            \
      (__attribute__((address_space(3))) unsigned int*)(lp), 16, 0, 0)

#define SBAR                                                                  \
  {                                                                           \
    __builtin_amdgcn_s_barrier();                                             \
    __builtin_amdgcn_sched_barrier(0);                                        \
  }
#define WAITV(n)                                                              \
  {                                                                           \
    asm volatile("s_waitcnt vmcnt(" #n ")" ::: "memory");                     \
    __builtin_amdgcn_sched_barrier(0);                                        \
  }
#define WAITL0                                                                \
  {                                                                           \
    asm volatile("s_waitcnt lgkmcnt(0)" ::: "memory");                        \
    __builtin_amdgcn_sched_barrier(0);                                        \
  }

// ===== Merged projection kernel (R14): Qp AND KV-proj in ONE 768-block
// launch. Blocks h<512: KV-proj (A=[WkT;WvT], B=xb, C=KVb[2048][16384],
// col-stripe XCD decode); h>=512: Qp (A=xb, B=WqT, C=Qp[16384][1024]).
// KVproj first (long pole); Qp fills the scheduling tail -> removes the
// inter-launch drain + a partial chip-round vs two launches.
// Core = R9/R13-measured-best: 256x256 tile, 16 waves, per-wave 64x64,
// BK=32, 3-slot 96KB ring, launch_bounds(1024,4) -> 64 VGPR ((1024,8)
// forces 32 VGPR + catastrophic spill, R10 - never again).
// Loop: {stage(t+2); 8 ds_read(t); lgkm0; 16 MFMA; vmcnt(2); s_barrier} -
// FIFO-proven lookahead-2, never vmcnt(0) in the loop.
// Swizzle phys = l ^ (((l>>7)&3)<<4) on BOTH pre-swizzled global source and
// ds_read address (involution; 0 bank conflicts measured).
__global__ __launch_bounds__(1024, 4) void proj_fused(
    const unsigned short* __restrict__ xb, const unsigned short* __restrict__ WT,
    unsigned short* __restrict__ QpO, unsigned short* __restrict__ KVbO,
    const float* __restrict__ bq, const float* __restrict__ bk,
    const float* __restrict__ bv) {
  __shared__ __attribute__((aligned(16))) char lds[3 * 32768];
  const int t = threadIdx.x;
  const int wave = t >> 6, lane = t & 63;
  const int wm = wave >> 2, wn = wave & 3;
  const int fr = lane & 15, fq = lane >> 4;

  const int h = blockIdx.x;
  const bool kv = (h < 512);
  const unsigned short* A;
  const unsigned short* B;
  unsigned short* Cc;
  long long ldc;
  int m0, n0;
  if (kv) {
    const int f = (h & 7) * 64 + (h >> 3);  // bijective XCD chunk over 512
    const int bx = f >> 3, by = f & 7;      // col-major: A (4MB) L2-resident
    m0 = by * 256;
    n0 = bx * 256;
    A = WT + 1024 * 1024;  // [WkT;WvT] rows 0..2047
    B = xb;
    Cc = KVbO;
    ldc = 16384;
  } else {
    const int hh = h - 512;
    const int f = (hh & 7) * 32 + (hh >> 3);  // chunk over 256
    const int bx = f & 3, by = f >> 2;
    m0 = by * 256;
    n0 = bx * 256;
    A = xb;
    B = WT;
    Cc = QpO;
    ldc = 1024;
  }

  const unsigned short* gA;
  const unsigned short* gB;
  {
    int d = t * 16;
    int l = d ^ (((d >> 7) & 3) << 4);
    int row = l >> 6, kel = (l & 63) >> 1;
    gA = A + (long long)(m0 + row) * 1024 + kel;
    gB = B + (long long)(n0 + row) * 1024 + kel;
  }

  const int slotx = (fr >> 1) & 3;
  const int acore = wm * 4096 + fr * 64 + ((fq ^ slotx) << 4);
  const int bcore = 16384 + wn * 4096 + fr * 64 + ((fq ^ slotx) << 4);

  f32x4 acc[4][4];
#pragma unroll
  for (int i = 0; i < 4; ++i)
#pragma unroll
    for (int j = 0; j < 4; ++j) acc[i][j] = (f32x4){0.f, 0.f, 0.f, 0.f};

  const int NT = 32;  // K=1024, BK=32

  auto stage = [&](int tile) {
    char* sb = lds + (tile % 3) * 32768 + wave * 1024;
    const int k0 = tile << 5;
    GL2LDS16(gA + k0, sb);
    GL2LDS16(gB + k0, sb + 16384);
  };

  stage(0);
  stage(1);
  WAITV(2);
  SBAR;

  bf16x8 av[4], bv4[4];
  for (int tt = 0; tt < NT - 2; ++tt) {
    const char* sb = lds + (tt % 3) * 32768;
    stage(tt + 2);
#pragma unroll
    for (int i = 0; i < 4; ++i) {
      av[i] = *(const bf16x8*)(sb + acore + i * 1024);
      bv4[i] = *(const bf16x8*)(sb + bcore + i * 1024);
    }
    WAITL0;
    __builtin_amdgcn_s_setprio(1);
#pragma unroll
    for (int mi = 0; mi < 4; ++mi)
#pragma unroll
      for (int ni = 0; ni < 4; ++ni)
        acc[mi][ni] = __builtin_amdgcn_mfma_f32_16x16x32_bf16(
            av[mi], bv4[ni], acc[mi][ni], 0, 0, 0);
    __builtin_amdgcn_s_setprio(0);
    WAITV(2);
    SBAR;
  }
  {
    const char* sb = lds + ((NT - 2) % 3) * 32768;
#pragma unroll
    for (int i = 0; i < 4; ++i) {
      av[i] = *(const bf16x8*)(sb + acore + i * 1024);
      bv4[i] = *(const bf16x8*)(sb + bcore + i * 1024);
    }
    WAITL0;
#pragma unroll
    for (int mi = 0; mi < 4; ++mi)
#pragma unroll
      for (int ni = 0; ni < 4; ++ni)
        acc[mi][ni] = __builtin_amdgcn_mfma_f32_16x16x32_bf16(
            av[mi], bv4[ni], acc[mi][ni], 0, 0, 0);
    WAITV(0);
    SBAR;
  }
  {
    const char* sb = lds + ((NT - 1) % 3) * 32768;
#pragma unroll
    for (int i = 0; i < 4; ++i) {
      av[i] = *(const bf16x8*)(sb + acore + i * 1024);
      bv4[i] = *(const bf16x8*)(sb + bcore + i * 1024);
    }
    WAITL0;
#pragma unroll
    for (int mi = 0; mi < 4; ++mi)
#pragma unroll
      for (int ni = 0; ni < 4; ++ni)
        acc[mi][ni] = __builtin_amdgcn_mfma_f32_16x16x32_bf16(
            av[mi], bv4[ni], acc[mi][ni], 0, 0, 0);
  }

  // epilogue. C/D: col = lane&15, row = (lane>>4)*4 + j [m89]
  const bool lower = (m0 < 1024);  // KV role: KpT half vs VT half
#pragma unroll
  for (int mi = 0; mi < 4; ++mi) {
    const int rbase = m0 + wm * 64 + mi * 16 + fq * 4;
    float rb[4];
#pragma unroll
    for (int j = 0; j < 4; ++j)
      if (kv) rb[j] = lower ? bk[rbase + j] : bv[rbase - 1024 + j];
#pragma unroll
    for (int ni = 0; ni < 4; ++ni) {
      const int c = n0 + wn * 64 + ni * 16 + fr;
      const float cb = kv ? 0.f : bq[c];
#pragma unroll
      for (int j = 0; j < 4; ++j) {
        float v = acc[mi][ni][j];
        v += kv ? rb[j] : cb;
        if (!kv || lower) v = (v > 0.f) ? v + 1.f : __expf(v);
        Cc[(long long)(rbase + j) * ldc + c] = f2bf(v);
      }
    }
  }
}

// ===== split-K KVt partials (unchanged R13 core, mode-3 only) =====
__global__ __launch_bounds__(1024, 4) void gemm_splitk(
    const unsigned short* __restrict__ A, const unsigned short* __restrict__ B,
    unsigned short* __restrict__ C) {
  __shared__ __attribute__((aligned(16))) char lds[3 * 32768];
  const int t = threadIdx.x;
  const int wave = t >> 6, lane = t & 63;
  const int wm = wave >> 2, wn = wave & 3;
  const int fr = lane & 15, fq = lane >> 4;

  const int gx = gridDim.x, gy = gridDim.y;
  int flat = blockIdx.y * gx + blockIdx.x;
  const int total = gx * gy;
  if ((total & 7) == 0) flat = (flat & 7) * (total >> 3) + (flat >> 3);
  const int bx = flat % gx, by = flat / gx;
  const int m0 = by * 256, n0 = bx * 256;

  const long long z = blockIdx.z;
  const long long koff = (z & 3) * 4096 + (z >> 2) * 1024;
  const unsigned short* Az = A + koff;
  const unsigned short* Bz = B + koff;

  const unsigned short* gA;
  const unsigned short* gB;
  {
    int d = t * 16;
    int l = d ^ (((d >> 7) & 3) << 4);
    int row = l >> 6, kel = (l & 63) >> 1;
    gA = Az + (long long)(m0 + row) * 16384 + kel;
    gB = Bz + (long long)(n0 + row) * 16384 + kel;
  }

  const int slotx = (fr >> 1) & 3;
  const int acore = wm * 4096 + fr * 64 + ((fq ^ slotx) << 4);
  const int bcore = 16384 + wn * 4096 + fr * 64 + ((fq ^ slotx) << 4);

  f32x4 acc[4][4];
#pragma unroll
  for (int i = 0; i < 4; ++i)
#pragma unroll
    for (int j = 0; j < 4; ++j) acc[i][j] = (f32x4){0.f, 0.f, 0.f, 0.f};

  const int NT = 32;

  auto stage = [&](int tile) {
    char* sb = lds + (tile % 3) * 32768 + wave * 1024;
    const int k0 = tile << 5;
    GL2LDS16(gA + k0, sb);
    GL2LDS16(gB + k0, sb + 16384);
  };

  stage(0);
  stage(1);
  WAITV(2);
  SBAR;

  bf16x8 av[4], bv[4];
  for (int tt = 0; tt < NT - 2; ++tt) {
    const char* sb = lds + (tt % 3) * 32768;
    stage(tt + 2);
#pragma unroll
    for (int i = 0; i < 4; ++i) {
      av[i] = *(const bf16x8*)(sb + acore + i * 1024);
      bv[i] = *(const bf16x8*)(sb + bcore + i * 1024);
    }
    WAITL0;
    __builtin_amdgcn_s_setprio(1);
#pragma unroll
    for (int mi = 0; mi < 4; ++mi)
#pragma unroll
      for (int ni = 0; ni < 4; ++ni)
        acc[mi][ni] = __builtin_amdgcn_mfma_f32_16x16x32_bf16(
            av[mi], bv[ni], acc[mi][ni], 0, 0, 0);
    __builtin_amdgcn_s_setprio(0);
    WAITV(2);
    SBAR;
  }
  {
    const char* sb = lds + ((NT - 2) % 3) * 32768;
#pragma unroll
    for (int i = 0; i < 4; ++i) {
      av[i] = *(const bf16x8*)(sb + acore + i * 1024);
      bv[i] = *(const bf16x8*)(sb + bcore + i * 1024);
    }
    WAITL0;
#pragma unroll
    for (int mi = 0; mi < 4; ++mi)
#pragma unroll
      for (int ni = 0; ni < 4; ++ni)
        acc[mi][ni] = __builtin_amdgcn_mfma_f32_16x16x32_bf16(
            av[mi], bv[ni], acc[mi][ni], 0, 0, 0);
    WAITV(0);
    SBAR;
  }
  {
    const char* sb = lds + ((NT - 1) % 3) * 32768;
#pragma unroll
    for (int i = 0; i < 4; ++i) {
      av[i] = *(const bf16x8*)(sb + acore + i * 1024);
      bv[i] = *(const bf16x8*)(sb + bcore + i * 1024);
    }
    WAITL0;
#pragma unroll
    for (int mi = 0; mi < 4; ++mi)
#pragma unroll
      for (int ni = 0; ni < 4; ++ni)
        acc[mi][ni] = __builtin_amdgcn_mfma_f32_16x16x32_bf16(
            av[mi], bv[ni], acc[mi][ni], 0, 0, 0);
  }

  unsigned short* Cu = C + z * 1048576ll;
#pragma unroll
  for (int mi = 0; mi < 4; ++mi) {
    const int rbase = m0 + wm * 64 + mi * 16 + fq * 4;
#pragma unroll
    for (int ni = 0; ni < 4; ++ni) {
      const int c = n0 + wn * 64 + ni * 16 + fr;
#pragma unroll
      for (int j = 0; j < 4; ++j)
        Cu[(long long)(rbase + j) * 1024 + c] = f2bf(acc[mi][ni][j]);
    }
  }
}

// ===== numerator: R13's 8-wave BK=64 4-phase kernel (unchanged) =====
__global__ __launch_bounds__(512, 2) void gemm_num(
    const unsigned short* __restrict__ A, long long aOffZ,
    const unsigned short* __restrict__ B, long long bOffZ,
    float* __restrict__ C, long long cOffZ,
    const float* __restrict__ norm, long long normOffZ) {
  const long long lda = 1024, ldb = 1024, ldc = 1024;
  const int K = 1024;
  __shared__ __attribute__((aligned(16))) char lds[2 * 65536];
  const int t = threadIdx.x;
  const int wave = t >> 6, lane = t & 63;
  const int wm = wave >> 2, wn = wave & 3;
  const int fr = lane & 15, fq = lane >> 4;

  const int gx = gridDim.x, gy = gridDim.y;
  int flat = blockIdx.y * gx + blockIdx.x;
  const int total = gx * gy;
  if ((total & 7) == 0) flat = (flat & 7) * (total >> 3) + (flat >> 3);
  const int bx = flat % gx, by = flat / gx;
  const int m0 = by * 256, n0 = bx * 256;

  const long long z = blockIdx.z;
  const unsigned short* Az = A + z * aOffZ;
  const unsigned short* Bz = B + z * bOffZ;

  const unsigned short* gA[2];
  const unsigned short* gB[2];
#pragma unroll
  for (int c = 0; c < 2; ++c) {
    int d = c * 8192 + t * 16;
    int l = d ^ (((d >> 7) & 3) << 4);
    int row = l >> 6, kel = (l & 63) >> 1;
    gA[c] = Az + (long long)(m0 + row) * lda + kel;
    gB[c] = Bz + (long long)(n0 + row) * ldb + kel;
  }

  const int slotx = (fr >> 1) & 3;
  const int acore = wm * 8192 + fr * 64 + ((fq ^ slotx) << 4);
  const int bcore = wn * 4096 + fr * 64 + ((fq ^ slotx) << 4);

  f32x4 acc[8][4];
#pragma unroll
  for (int i = 0; i < 8; ++i)
#pragma unroll
    for (int j = 0; j < 4; ++j) acc[i][j] = (f32x4){0.f, 0.f, 0.f, 0.f};

  const int NT = K >> 6;

  auto stage_sub = [&](int tile, int which) {
    char* dst = lds + (tile & 1) * 65536 + which * 16384 + wave * 1024;
    const int kofs = (tile << 6) + ((which >> 1) << 5);
    if (which & 1) {
      GL2LDS16(gB[0] + kofs, dst);
      GL2LDS16(gB[1] + kofs, dst + 8192);
    } else {
      GL2LDS16(gA[0] + kofs, dst);
      GL2LDS16(gA[1] + kofs, dst + 8192);
    }
  };

  stage_sub(0, 0);
  stage_sub(0, 1);
  stage_sub(0, 2);
  stage_sub(0, 3);
  WAITV(4);
  SBAR;

  bf16x8 av[4], bv0[4], bv1[4];
  for (int tt = 0; tt < NT - 1; ++tt) {
    const char* bufp = lds + (tt & 1) * 65536;
#pragma unroll
    for (int i = 0; i < 4; ++i) {
      av[i] = *(const bf16x8*)(bufp + acore + i * 1024);
      bv0[i] = *(const bf16x8*)(bufp + 16384 + bcore + i * 1024);
    }
    stage_sub(tt + 1, 0);
    SBAR;
    WAITL0;
    __builtin_amdgcn_s_setprio(1);
#pragma unroll
    for (int mi = 0; mi < 4; ++mi)
#pragma unroll
      for (int ni = 0; ni < 4; ++ni)
        acc[mi][ni] = __builtin_amdgcn_mfma_f32_16x16x32_bf16(
            av[mi], bv0[ni], acc[mi][ni], 0, 0, 0);
    __builtin_amdgcn_s_setprio(0);
    SBAR;
#pragma unroll
    for (int i = 0; i < 4; ++i)
      av[i] = *(const bf16x8*)(bufp + acore + (4 + i) * 1024);
    stage_sub(tt + 1, 1);
    SBAR;
    WAITL0;
    __builtin_amdgcn_s_setprio(1);
#pragma unroll
    for (int mi = 0; mi < 4; ++mi)
#pragma unroll
      for (int ni = 0; ni < 4; ++ni)
        acc[4 + mi][ni] = __builtin_amdgcn_mfma_f32_16x16x32_bf16(
            av[mi], bv0[ni], acc[4 + mi][ni], 0, 0, 0);
    __builtin_amdgcn_s_setprio(0);
    WAITV(4);
    SBAR;
#pragma unroll
    for (int i = 0; i < 4; ++i) {
      av[i] = *(const bf16x8*)(bufp + 32768 + acore + i * 1024);
      bv1[i] = *(const bf16x8*)(bufp + 49152 + bcore + i * 1024);
    }
    stage_sub(tt + 1, 2);
    SBAR;
    WAITL0;
    __builtin_amdgcn_s_setprio(1);
#pragma unroll
    for (int mi = 0; mi < 4; ++mi)
#pragma unroll
      for (int ni = 0; ni < 4; ++ni)
        acc[mi][ni] = __builtin_amdgcn_mfma_f32_16x16x32_bf16(
            av[mi], bv1[ni], acc[mi][ni], 0, 0, 0);
    __builtin_amdgcn_s_setprio(0);
    SBAR;
#pragma unroll
    for (int i = 0; i < 4; ++i)
      av[i] = *(const bf16x8*)(bufp + 32768 + acore + (4 + i) * 1024);
    stage_sub(tt + 1, 3);
    SBAR;
    WAITL0;
    __builtin_amdgcn_s_setprio(1);
#pragma unroll
    for (int mi = 0; mi < 4; ++mi)
#pragma unroll
      for (int ni = 0; ni < 4; ++ni)
        acc[4 + mi][ni] = __builtin_amdgcn_mfma_f32_16x16x32_bf16(
            av[mi], bv1[ni], acc[4 + mi][ni], 0, 0, 0);
    __builtin_amdgcn_s_setprio(0);
    WAITV(4);
    SBAR;
  }
  {
    const char* bufp = lds + ((NT - 1) & 1) * 65536;
#pragma unroll
    for (int i = 0; i < 4; ++i) {
      av[i] = *(const bf16x8*)(bufp + acore + i * 1024);
      bv0[i] = *(const bf16x8*)(bufp + 16384 + bcore + i * 1024);
    }
    SBAR;
    WAITL0;
#pragma unroll
    for (int mi = 0; mi < 4; ++mi)
#pragma unroll
      for (int ni = 0; ni < 4; ++ni)
        acc[mi][ni] = __builtin_amdgcn_mfma_f32_16x16x32_bf16(
            av[mi], bv0[ni], acc[mi][ni], 0, 0, 0);
    SBAR;
#pragma unroll
    for (int i = 0; i < 4; ++i)
      av[i] = *(const bf16x8*)(bufp + acore + (4 + i) * 1024);
    SBAR;
    WAITL0;
#pragma unroll
    for (int mi = 0; mi < 4; ++mi)
#pragma unroll
      for (int ni = 0; ni < 4; ++ni)
        acc[4 + mi][ni] = __builtin_amdgcn_mfma_f32_16x16x32_bf16(
            av[mi], bv0[ni], acc[4 + mi][ni], 0, 0, 0);
    WAITV(0);
    SBAR;
#pragma unroll
    for (int i = 0; i < 4; ++i) {
      av[i] = *(const bf16x8*)(bufp + 32768 + acore + i * 1024);
      bv1[i] = *(const bf16x8*)(bufp + 49152 + bcore + i * 1024);
    }
    WAITL0;
#pragma unroll
    for (int mi = 0; mi < 4; ++mi)
#pragma unroll
      for (int ni = 0; ni < 4; ++ni)
        acc[mi][ni] = __builtin_amdgcn_mfma_f32_16x16x32_bf16(
            av[mi], bv1[ni], acc[mi][ni], 0, 0, 0);
#pragma unroll
    for (int i = 0; i < 4; ++i)
      av[i] = *(const bf16x8*)(bufp + 32768 + acore + (4 + i) * 1024);
    WAITL0;
#pragma unroll
    for (int mi = 0; mi < 4; ++mi)
#pragma unroll
      for (int ni = 0; ni < 4; ++ni)
        acc[4 + mi][ni] = __builtin_amdgcn_mfma_f32_16x16x32_bf16(
            av[mi], bv1[ni], acc[4 + mi][ni], 0, 0, 0);
  }

  const float* nrmz = norm + z * normOffZ;
  float* Cf = C + z * cOffZ;
#pragma unroll
  for (int mi = 0; mi < 8; ++mi) {
    const int rbase = m0 + wm * 128 + mi * 16 + fq * 4;
    float nv[4];
#pragma unroll
    for (int j = 0; j < 4; ++j) nv[j] = nrmz[rbase + j];
#pragma unroll
    for (int ni = 0; ni < 4; ++ni) {
      const int c = n0 + wn * 64 + ni * 16 + fr;
#pragma unroll
      for (int j = 0; j < 4; ++j)
        Cf[(long long)(rbase + j) * ldc + c] = acc[mi][ni][j] / nv[j];
    }
  }
}

// ===== prep: 3x W-transpose + x->bf16 convert in one launch (z in 0..3) ===
__global__ __launch_bounds__(256) void prep_fused(
    const float* __restrict__ Wq, const float* __restrict__ Wk,
    const float* __restrict__ Wv, unsigned short* __restrict__ WT,
    const float4* __restrict__ x4, uint2* __restrict__ xb4) {
  __shared__ float tile[32][33];
  if (blockIdx.z < 3) {
    const float* W = blockIdx.z == 0 ? Wq : (blockIdx.z == 1 ? Wk : Wv);
    unsigned short* out = WT + (size_t)blockIdx.z * 1024 * 1024;
    const int tx = threadIdx.x & 31, ty = threadIdx.x >> 5;
    const int i0 = blockIdx.y * 32, o0 = blockIdx.x * 32;
#pragma unroll
    for (int s = 0; s < 32; s += 8)
      tile[ty + s][tx] = W[(long long)(i0 + ty + s) * 1024 + o0 + tx];
    __syncthreads();
#pragma unroll
    for (int s = 0; s < 32; s += 8)
      out[(long long)(o0 + ty + s) * 1024 + i0 + tx] = f2bf(tile[tx][ty + s]);
  } else {
    const int flat = blockIdx.y * 32 + blockIdx.x;  // 0..1023
    const int n4 = 4194304;                          // 16384*1024/4
    for (int i = flat * 256 + threadIdx.x; i < n4; i += 1024 * 256) {
      float4 v = x4[i];
      uint2 o;
      o.x = (unsigned)f2bf(v.x) | ((unsigned)f2bf(v.y) << 16);
      o.y = (unsigned)f2bf(v.z) | ((unsigned)f2bf(v.w) << 16);
      xb4[i] = o;
    }
  }
}

// K_sum[b][d] = sum_n KpT[d][b*4096 + n]
__global__ __launch_bounds__(256) void ksum_kernel(
    const unsigned short* __restrict__ KpT, float* __restrict__ Ksum) {
  const int gw = (blockIdx.x * 256 + threadIdx.x) >> 6;
  const int lane = threadIdx.x & 63;
  const int d = gw >> 2, b = gw & 3;
  const unsigned short* p = KpT + (long long)d * 16384 + b * 4096 + lane * 8;
  float s = 0.f;
#pragma unroll
  for (int it = 0; it < 8; ++it) {
    u16x8 v = *(const u16x8*)(p + it * 512);
#pragma unroll
    for (int j = 0; j < 8; ++j) s += bf2f(v[j]);
  }
#pragma unroll
  for (int o = 32; o > 0; o >>= 1) s += __shfl_down(s, o, 64);
  if (lane == 0) Ksum[b * 1024 + d] = s;
}

// ===== tail: KVt reduce (blocks <2048) + norm (blocks >=2048), one launch ==
__global__ __launch_bounds__(256) void tail_fused(
    const unsigned short* __restrict__ P, unsigned short* __restrict__ KVt,
    const unsigned short* __restrict__ Qp, const float* __restrict__ Ksum,
    float* __restrict__ nrm) {
  if (blockIdx.x < 2048) {
    const long long i = ((long long)blockIdx.x * 256 + threadIdx.x) * 8;
    const int b = (int)(i >> 20);
    const long long ed = i & ((1ll << 20) - 1);
    float s[8] = {0.f, 0.f, 0.f, 0.f, 0.f, 0.f, 0.f, 0.f};
#pragma unroll
    for (int ks = 0; ks < 4; ++ks) {
      u16x8 v = *(const u16x8*)(P + ((long long)(ks * 4 + b) << 20) + ed);
#pragma unroll
      for (int j = 0; j < 8; ++j) s[j] += bf2f(v[j]);
    }
    u16x8 o;
#pragma unroll
    for (int j = 0; j < 8; ++j) o[j] = f2bf(s[j]);
    *(u16x8*)(KVt + i) = o;
  } else {
    const int gw = ((blockIdx.x - 2048) * 256 + threadIdx.x) >> 6;
    const int lane = threadIdx.x & 63;
    const int b = gw >> 12;
    const unsigned short* q = Qp + (long long)gw * 1024 + lane * 8;
    const float* ks = Ksum + b * 1024 + lane * 8;
    float s = 0.f;
#pragma unroll
    for (int it = 0; it < 2; ++it) {
      u16x8 v = *(const u16x8*)(q + it * 512);
      float4 k0 = *(const float4*)(ks + it * 512);
      float4 k1 = *(const float4*)(ks + it * 512 + 4);
      s += bf2f(v[0]) * k0.x + bf2f(v[1]) * k0.y + bf2f(v[2]) * k0.z +
           bf2f(v[3]) * k0.w + bf2f(v[4]) * k1.x + bf2f(v[5]) * k1.y +
           bf2f(v[6]) * k1.z + bf2f(v[7]) * k1.w;
    }
#pragma unroll
    for (int o = 32; o > 0; o >>= 1) s += __shfl_down(s, o, 64);
    if (lane == 0) nrm[gw] = s + 1e-6f;
  }
}

extern "C" void kernel_launch(void* const* d_in, const int* in_sizes, int n_in,
                              void* d_out, int out_size, void* d_ws,
                              size_t ws_size, hipStream_t stream) {
  const float* x  = (const float*)d_in[0];
  const float* Wq = (const float*)d_in[1];
  const float* bq = (const float*)d_in[2];
  const float* Wk = (const float*)d_in[3];
  const float* bk = (const float*)d_in[4];
  const float* Wv = (const float*)d_in[5];
  const float* bv = (const float*)d_in[6];
  float* out = (float*)d_out;

  const size_t MN = 16384ull * 1024ull;
  char* w = (char*)d_ws;
  unsigned short* xb  = (unsigned short*)w;  w += MN * 2;
  unsigned short* WT  = (unsigned short*)w;  w += 3ull * 1024 * 1024 * 2;
  unsigned short* Qp  = (unsigned short*)w;  w += MN * 2;
  unsigned short* KVb = (unsigned short*)w;  w += 2 * MN * 2;
  unsigned short* KVt = (unsigned short*)w;  w += 4ull * 1024 * 1024 * 2;
  float* Ksum = (float*)w;  w += 4ull * 1024 * 4;
  float* nrm  = (float*)w;  w += 16384ull * 4;
  unsigned short* Pkv = xb;  // split-K partials alias dead xb
  unsigned short* KpT = KVb;
  unsigned short* VT  = KVb + MN;

  // 1) W transposes + x conversion (one launch)
  prep_fused<<<dim3(32, 32, 4), 256, 0, stream>>>(Wq, Wk, Wv, WT,
                                                  (const float4*)x, (uint2*)xb);
  // 2) Qp + merged KV projection (one 768-block launch; KVproj first)
  proj_fused<<<768, 1024, 0, stream>>>(xb, WT, Qp, KVb, bq, bk, bv);
  // 3) K_sum
  ksum_kernel<<<1024, 256, 0, stream>>>(KpT, Ksum);
  // 4) split-K KVt partials: z = ks*4+b
  gemm_splitk<<<dim3(4, 4, 16), 1024, 0, stream>>>(VT, KpT, Pkv);
  // 5) KVt reduce + norm (one launch)
  tail_fused<<<6144, 256, 0, stream>>>(Pkv, KVt, Qp, Ksum, nrm);
  // 6) numerator
  gemm_num<<<dim3(4, 16, 4), 512, 0, stream>>>(
      Qp, 4096ll * 1024, KVt, 1024 * 1024, out, 4096ll * 1024, nrm, 4096);
}